// Round 3
// 455.389 us; speedup vs baseline: 1.1275x; 1.1275x over previous
//
#include <hip/hip_runtime.h>
#include <cstddef>

#define T_TOK 512
#define D_DIM 1024
#define E_EXP 64
#define INTER 512
#define TOPK 4

typedef __bf16 bf16x8 __attribute__((ext_vector_type(8)));
typedef __bf16 bf16x4 __attribute__((ext_vector_type(4)));
typedef float f32x4 __attribute__((ext_vector_type(4)));

// async global->LDS, 16B per lane; LDS dst is wave-uniform base + lane*16.
__device__ __forceinline__ void async16(float4* ldsdst, const void* g) {
  __builtin_amdgcn_global_load_lds(
      (const __attribute__((address_space(1))) void*)g,
      (__attribute__((address_space(3))) void*)ldsdst, 16, 0, 0);
}

// Split 8 consecutive fp32 (two float4) into hi/lo bf16x8 fragments.
// hi = RNE bf16 of x, lo = RNE bf16 of (x - hi); hi+lo carries ~16 mantissa
// bits, so wh*xh + wh*xl + wl*xh reproduces fp32 GEMM to ~1e-4 absolute.
__device__ __forceinline__ void cvt_split8(const float4 a, const float4 b,
                                           bf16x8& h, bf16x8& l) {
  float f[8] = {a.x, a.y, a.z, a.w, b.x, b.y, b.z, b.w};
#pragma unroll
  for (int i = 0; i < 8; i++) {
    const __bf16 hv = (__bf16)f[i];
    h[i] = hv;
    l[i] = (__bf16)(f[i] - (float)hv);
  }
}

// ---------------- Router: 1 wave per token; also pre-splits x ----------------
__global__ __launch_bounds__(64) void router_kernel(
    const float* __restrict__ x, const float* __restrict__ gate_w,
    int* __restrict__ cnt, int* __restrict__ list, float* __restrict__ pairw,
    __bf16* __restrict__ x_hi, __bf16* __restrict__ x_lo) {
  const int t = blockIdx.x;
  const int e = threadIdx.x;
  const float4* xr = (const float4*)(x + (size_t)t * D_DIM);
  const float4* gr = (const float4*)(gate_w + (size_t)e * D_DIM);
  float acc = 0.f;
#pragma unroll 8
  for (int i = 0; i < D_DIM / 4; i++) {
    float4 a = xr[i], b = gr[i];
    acc += a.x * b.x + a.y * b.y + a.z * b.z + a.w * b.w;
  }
  // pre-split this row of x: lane e handles elems [e*16, e*16+16) (L1-hot)
  {
    bf16x8 h0, l0, h1, l1;
    cvt_split8(xr[e * 4 + 0], xr[e * 4 + 1], h0, l0);
    cvt_split8(xr[e * 4 + 2], xr[e * 4 + 3], h1, l1);
    __bf16* xh = x_hi + (size_t)t * D_DIM + e * 16;
    __bf16* xl = x_lo + (size_t)t * D_DIM + e * 16;
    *(bf16x8*)(xh) = h0; *(bf16x8*)(xh + 8) = h1;
    *(bf16x8*)(xl) = l0; *(bf16x8*)(xl + 8) = l1;
  }
  float m = acc;
  for (int off = 32; off; off >>= 1) m = fmaxf(m, __shfl_xor(m, off, 64));
  float p = __expf(acc - m);
  float s = p;
  for (int off = 32; off; off >>= 1) s += __shfl_xor(s, off, 64);
  float prob = p / s;

  float val = prob;
  int ids[TOPK];
  float ws[TOPK];
  float wsum = 0.f;
#pragma unroll
  for (int k = 0; k < TOPK; k++) {
    float v = val;
    int idx = e;
    for (int off = 32; off; off >>= 1) {
      float ov = __shfl_xor(v, off, 64);
      int oi = __shfl_xor(idx, off, 64);
      if (ov > v || (ov == v && oi < idx)) { v = ov; idx = oi; }
    }
    ids[k] = idx;
    ws[k] = v;
    wsum += v;
    if (e == idx) val = -1.f;
  }
  if (e < TOPK) {
    const int k = e;
    const int ex = ids[k];
    const float w = ws[k] / wsum;
    const int p_id = t * TOPK + k;
    pairw[p_id] = w;
    const int pos = atomicAdd(&cnt[ex], 1);
    list[ex * T_TOK + pos] = p_id;
  }
}

// ---------------- Stage 1: gate+up GEMM + SiLU (split-bf16 MFMA) ----------
// grid (E=64, INTER/32=16), 256 threads (4 waves). Tile 32f x 64t, BK=64.
// LDS (bf16, 16B units, per buffer of 2048 units = 32KB):
//   wg_hi [0,256) wg_lo [256,512) wu_hi [512,768) wu_lo [768,1024)
//   xt_hi [1024,1536) xt_lo [1536,2048)
// XOR swizzle: data (row, blk8) at phys unit row*8 + (blk ^ (row&7)).
// Weights: reg-staged fp32 -> convert once -> bf16 LDS (T14 split: loads
// issued post-barrier, convert+ds_write post-compute). x: DMA'd from
// pre-split x_hi/x_lo with inverse-swizzled per-lane source.
// Inner loop: pure ds_read_b128 + MFMA (3-product fp32 emulation).
#define BF1 32
#define BT1 64
#define NK1 (D_DIM / 64)
__global__ __launch_bounds__(256) void stage1_kernel(
    const __bf16* __restrict__ x_hi, const __bf16* __restrict__ x_lo,
    const float* __restrict__ w_gate, const float* __restrict__ w_up,
    const int* __restrict__ cnt, const int* __restrict__ list,
    const float* __restrict__ pairw,
    __bf16* __restrict__ h_hi, __bf16* __restrict__ h_lo) {
  const int e = blockIdx.x;
  const int fbase = blockIdx.y * BF1;
  const int n = cnt[e];
  if (n == 0) return;
  __shared__ float4 lds[2][2048];  // 64 KB
  const int tid = threadIdx.x;
  const int w = tid >> 6;
  const int lane = tid & 63;
  const int lrow = lane & 15;
  const int lk = lane >> 4;
  const int* mylist = list + e * T_TOK;

  // weight reg-staging: thread owns (wg row wrow, blk wblk) and wu same pos
  const int wrow = tid >> 3;  // 0..31
  const int wblk = tid & 7;
  const float* gsrc = w_gate + ((size_t)e * INTER + fbase + wrow) * D_DIM + wblk * 8;
  const float* usrc = w_up + ((size_t)e * INTER + fbase + wrow) * D_DIM + wblk * 8;
  const int wunit = wrow * 8 + (wblk ^ (wrow & 7));

  float4 wreg[4];

  for (int tb = 0; tb < n; tb += BT1) {
    // x DMA per-lane sources (inverse-swizzled): wave w owns units
    // [w*256, w*256+256) of the 1024 xt units (u<512: hi, else lo).
    const __bf16* xsrc[4];
#pragma unroll
    for (int r = 0; r < 4; r++) {
      const int u = w * 256 + r * 64 + lane;
      const int uu = u & 511;
      const int row = uu >> 3;
      const int blk = (uu & 7) ^ (row & 7);
      const int slot = tb + row;
      const int pid = mylist[slot < n ? slot : 0];
      const __bf16* base = (u < 512) ? x_hi : x_lo;
      xsrc[r] = base + (size_t)(pid >> 2) * D_DIM + blk * 8;
    }

    auto stage_load = [&](int buf, int kb) {
      // weight loads first (so converts need not wait the DMA below)
      const float4* g4 = (const float4*)(gsrc + kb);
      const float4* u4 = (const float4*)(usrc + kb);
      wreg[0] = g4[0]; wreg[1] = g4[1];
      wreg[2] = u4[0]; wreg[3] = u4[1];
      float4* B = &lds[buf][0];
#pragma unroll
      for (int r = 0; r < 4; r++)
        async16(B + 1024 + w * 256 + r * 64, xsrc[r] + kb);
    };
    auto convert_write = [&](int buf) {
      __bf16* L = (__bf16*)&lds[buf][0];
      bf16x8 h0, l0;
      cvt_split8(wreg[0], wreg[1], h0, l0);
      *(bf16x8*)(L + (size_t)wunit * 8) = h0;
      *(bf16x8*)(L + (size_t)(wunit + 256) * 8) = l0;
      cvt_split8(wreg[2], wreg[3], h0, l0);
      *(bf16x8*)(L + (size_t)(wunit + 512) * 8) = h0;
      *(bf16x8*)(L + (size_t)(wunit + 768) * 8) = l0;
    };

    f32x4 accg[2] = {};
    f32x4 accu[2] = {};
    const bool active = (tb + w * 16) < n;

    stage_load(0, 0);
    convert_write(0);
    for (int ki = 0; ki < NK1; ki++) {
      __syncthreads();  // buf[ki&1] staged (DMA drained by barrier waitcnt)
      if (ki + 1 < NK1) stage_load((ki + 1) & 1, (ki + 1) * 64);
      if (active) {
        const __bf16* L = (const __bf16*)&lds[ki & 1][0];
#pragma unroll
        for (int s = 0; s < 2; s++) {
          const int blk = s * 4 + lk;
          const int xr = w * 16 + lrow;
          const int xu = xr * 8 + (blk ^ (xr & 7));
          const bf16x8 xh = *(const bf16x8*)(L + (size_t)(1024 + xu) * 8);
          const bf16x8 xl = *(const bf16x8*)(L + (size_t)(1536 + xu) * 8);
#pragma unroll
          for (int i = 0; i < 2; i++) {
            const int fr = i * 16 + lrow;
            const int fu = fr * 8 + (blk ^ (fr & 7));
            const bf16x8 gh = *(const bf16x8*)(L + (size_t)fu * 8);
            const bf16x8 gl = *(const bf16x8*)(L + (size_t)(256 + fu) * 8);
            const bf16x8 uh = *(const bf16x8*)(L + (size_t)(512 + fu) * 8);
            const bf16x8 ul = *(const bf16x8*)(L + (size_t)(768 + fu) * 8);
            accg[i] = __builtin_amdgcn_mfma_f32_16x16x32_bf16(gh, xh, accg[i], 0, 0, 0);
            accg[i] = __builtin_amdgcn_mfma_f32_16x16x32_bf16(gh, xl, accg[i], 0, 0, 0);
            accg[i] = __builtin_amdgcn_mfma_f32_16x16x32_bf16(gl, xh, accg[i], 0, 0, 0);
            accu[i] = __builtin_amdgcn_mfma_f32_16x16x32_bf16(uh, xh, accu[i], 0, 0, 0);
            accu[i] = __builtin_amdgcn_mfma_f32_16x16x32_bf16(uh, xl, accu[i], 0, 0, 0);
            accu[i] = __builtin_amdgcn_mfma_f32_16x16x32_bf16(ul, xh, accu[i], 0, 0, 0);
          }
        }
      }
      if (ki + 1 < NK1) convert_write((ki + 1) & 1);
    }
    // epilogue: h[p][f] = w_p * silu(g) * u, written as bf16 hi/lo split.
    // D frag: token = lane&15 (wave's group), f = i*16 + lk*4 + r
    const int slot = tb + w * 16 + lrow;
    if (slot < n) {
      const int pid = mylist[slot];
      const float wp = pairw[pid];
      __bf16* hh = h_hi + (size_t)pid * INTER + fbase;
      __bf16* hl = h_lo + (size_t)pid * INTER + fbase;
#pragma unroll
      for (int i = 0; i < 2; i++) {
        bf16x4 vh, vl;
#pragma unroll
        for (int r = 0; r < 4; r++) {
          const float g = accg[i][r];
          const float u = accu[i][r];
          const float v = wp * (g / (1.f + __expf(-g))) * u;
          const __bf16 hv = (__bf16)v;
          vh[r] = hv;
          vl[r] = (__bf16)(v - (float)hv);
        }
        *(bf16x4*)(hh + i * 16 + lk * 4) = vh;
        *(bf16x4*)(hl + i * 16 + lk * 4) = vl;
      }
    }
  }
}

// ---------------- Stage 2: down GEMM (split-bf16 MFMA), atomic accum ------
// grid (E=64, D/64=16), 256 threads. Tile 64d x 64t, BK=64.
// LDS units per buffer: wd_hi [0,512) wd_lo [512,1024) ht_hi [1024,1536)
// ht_lo [1536,2048). wd reg-staged+converted; ht DMA'd from pre-split h.
#define BF2 64
#define NK2 (INTER / 64)
__global__ __launch_bounds__(256) void stage2_kernel(
    const float* __restrict__ w_down, const int* __restrict__ cnt,
    const int* __restrict__ list, const __bf16* __restrict__ h_hi,
    const __bf16* __restrict__ h_lo, float* __restrict__ out) {
  const int e = blockIdx.x;
  const int dbase = blockIdx.y * BF2;
  const int n = cnt[e];
  if (n == 0) return;
  __shared__ float4 lds[2][2048];  // 64 KB
  const int tid = threadIdx.x;
  const int w = tid >> 6;
  const int lane = tid & 63;
  const int lrow = lane & 15;
  const int lk = lane >> 4;
  const int* mylist = list + e * T_TOK;

  // wd reg-staging: thread owns rows wrow and wrow+32 at blk wblk
  const int wrow = tid >> 3;  // 0..31
  const int wblk = tid & 7;
  const float* dsrc0 = w_down + ((size_t)e * D_DIM + dbase + wrow) * INTER + wblk * 8;
  const float* dsrc1 = w_down + ((size_t)e * D_DIM + dbase + wrow + 32) * INTER + wblk * 8;
  const int wunit0 = wrow * 8 + (wblk ^ (wrow & 7));
  const int wunit1 = wunit0 + 256;  // (wrow+32)&7 == wrow&7

  float4 wreg[4];

  for (int tb = 0; tb < n; tb += BT1) {
    const __bf16* hsrc[4];
#pragma unroll
    for (int r = 0; r < 4; r++) {
      const int u = w * 256 + r * 64 + lane;
      const int uu = u & 511;
      const int row = uu >> 3;
      const int blk = (uu & 7) ^ (row & 7);
      const int slot = tb + row;
      const int pid = mylist[slot < n ? slot : 0];
      const __bf16* base = (u < 512) ? h_hi : h_lo;
      hsrc[r] = base + (size_t)pid * INTER + blk * 8;
    }

    auto stage_load = [&](int buf, int kb) {
      const float4* a4 = (const float4*)(dsrc0 + kb);
      const float4* b4 = (const float4*)(dsrc1 + kb);
      wreg[0] = a4[0]; wreg[1] = a4[1];
      wreg[2] = b4[0]; wreg[3] = b4[1];
      float4* B = &lds[buf][0];
#pragma unroll
      for (int r = 0; r < 4; r++)
        async16(B + 1024 + w * 256 + r * 64, hsrc[r] + kb);
    };
    auto convert_write = [&](int buf) {
      __bf16* L = (__bf16*)&lds[buf][0];
      bf16x8 h0, l0;
      cvt_split8(wreg[0], wreg[1], h0, l0);
      *(bf16x8*)(L + (size_t)wunit0 * 8) = h0;
      *(bf16x8*)(L + (size_t)(wunit0 + 512) * 8) = l0;
      cvt_split8(wreg[2], wreg[3], h0, l0);
      *(bf16x8*)(L + (size_t)wunit1 * 8) = h0;
      *(bf16x8*)(L + (size_t)(wunit1 + 512) * 8) = l0;
    };

    f32x4 acc[4] = {};
    const bool active = (tb + w * 16) < n;

    stage_load(0, 0);
    convert_write(0);
    for (int ki = 0; ki < NK2; ki++) {
      __syncthreads();
      if (ki + 1 < NK2) stage_load((ki + 1) & 1, (ki + 1) * 64);
      if (active) {
        const __bf16* L = (const __bf16*)&lds[ki & 1][0];
#pragma unroll
        for (int s = 0; s < 2; s++) {
          const int blk = s * 4 + lk;
          const int hr = w * 16 + lrow;
          const int hu = hr * 8 + (blk ^ (hr & 7));
          const bf16x8 hh = *(const bf16x8*)(L + (size_t)(1024 + hu) * 8);
          const bf16x8 hl = *(const bf16x8*)(L + (size_t)(1536 + hu) * 8);
#pragma unroll
          for (int i = 0; i < 4; i++) {
            const int dr = i * 16 + lrow;
            const int du = dr * 8 + (blk ^ (dr & 7));
            const bf16x8 wh = *(const bf16x8*)(L + (size_t)du * 8);
            const bf16x8 wl = *(const bf16x8*)(L + (size_t)(512 + du) * 8);
            acc[i] = __builtin_amdgcn_mfma_f32_16x16x32_bf16(wh, hh, acc[i], 0, 0, 0);
            acc[i] = __builtin_amdgcn_mfma_f32_16x16x32_bf16(wh, hl, acc[i], 0, 0, 0);
            acc[i] = __builtin_amdgcn_mfma_f32_16x16x32_bf16(wl, hh, acc[i], 0, 0, 0);
          }
        }
      }
      if (ki + 1 < NK2) convert_write((ki + 1) & 1);
    }
    // epilogue: atomic accumulate (combine weight folded into h)
    const int slot = tb + w * 16 + lrow;
    if (slot < n) {
      const int tok = mylist[slot] >> 2;
      float* op = out + (size_t)tok * D_DIM + dbase;
#pragma unroll
      for (int i = 0; i < 4; i++) {
#pragma unroll
        for (int r = 0; r < 4; r++)
          atomicAdd(&op[i * 16 + lk * 4 + r], acc[i][r]);
      }
    }
  }
}

extern "C" void kernel_launch(void* const* d_in, const int* in_sizes, int n_in,
                              void* d_out, int out_size, void* d_ws, size_t ws_size,
                              hipStream_t stream) {
  const float* x = (const float*)d_in[0];
  const float* gate_w = (const float*)d_in[1];
  const float* w_gate = (const float*)d_in[2];
  const float* w_up = (const float*)d_in[3];
  const float* w_down = (const float*)d_in[4];
  float* out = (float*)d_out;

  char* ws = (char*)d_ws;
  size_t off = 0;
  int* cnt = (int*)(ws + off); off += 256;
  int* list = (int*)(ws + off); off += (size_t)E_EXP * T_TOK * 4;
  float* pairw = (float*)(ws + off); off += (size_t)T_TOK * TOPK * 4;
  __bf16* h_hi = (__bf16*)(ws + off); off += (size_t)T_TOK * TOPK * INTER * 2;
  __bf16* h_lo = (__bf16*)(ws + off); off += (size_t)T_TOK * TOPK * INTER * 2;
  __bf16* x_hi = (__bf16*)(ws + off); off += (size_t)T_TOK * D_DIM * 2;
  __bf16* x_lo = (__bf16*)(ws + off); off += (size_t)T_TOK * D_DIM * 2;

  hipMemsetAsync(cnt, 0, E_EXP * sizeof(int), stream);
  hipMemsetAsync(out, 0, (size_t)T_TOK * D_DIM * sizeof(float), stream);

  router_kernel<<<T_TOK, 64, 0, stream>>>(x, gate_w, cnt, list, pairw, x_hi, x_lo);
  stage1_kernel<<<dim3(E_EXP, INTER / BF1), 256, 0, stream>>>(
      x_hi, x_lo, w_gate, w_up, cnt, list, pairw, h_hi, h_lo);
  stage2_kernel<<<dim3(E_EXP, D_DIM / BF2), 256, 0, stream>>>(
      w_down, cnt, list, h_hi, h_lo, out);
}

// Round 6
// 437.657 us; speedup vs baseline: 1.1732x; 1.0405x over previous
//
#include <hip/hip_runtime.h>
#include <cstddef>

#define T_TOK 512
#define D_DIM 1024
#define E_EXP 64
#define INTER 512
#define TOPK 4

typedef __bf16 bf16x8 __attribute__((ext_vector_type(8)));
typedef __bf16 bf16x4 __attribute__((ext_vector_type(4)));
typedef float f32x4 __attribute__((ext_vector_type(4)));

// Split 8 consecutive fp32 (two float4) into hi/lo bf16x8 fragments.
// hi = RNE bf16 of x, lo = RNE bf16 of (x - hi); hi+lo carries ~16 mantissa
// bits, so wh*xh + wh*xl + wl*xh reproduces fp32 GEMM to ~1e-4 absolute.
__device__ __forceinline__ void cvt_split8(const float4 a, const float4 b,
                                           bf16x8& h, bf16x8& l) {
  float f[8] = {a.x, a.y, a.z, a.w, b.x, b.y, b.z, b.w};
#pragma unroll
  for (int i = 0; i < 8; i++) {
    const __bf16 hv = (__bf16)f[i];
    h[i] = hv;
    l[i] = (__bf16)(f[i] - (float)hv);
  }
}

// ---------------- Router: 1 wave per token; also pre-splits x ----------------
__global__ __launch_bounds__(64) void router_kernel(
    const float* __restrict__ x, const float* __restrict__ gate_w,
    int* __restrict__ cnt, int* __restrict__ list, float* __restrict__ pairw,
    __bf16* __restrict__ x_hi, __bf16* __restrict__ x_lo) {
  const int t = blockIdx.x;
  const int e = threadIdx.x;
  const float4* xr = (const float4*)(x + (size_t)t * D_DIM);
  const float4* gr = (const float4*)(gate_w + (size_t)e * D_DIM);
  float acc = 0.f;
#pragma unroll 8
  for (int i = 0; i < D_DIM / 4; i++) {
    float4 a = xr[i], b = gr[i];
    acc += a.x * b.x + a.y * b.y + a.z * b.z + a.w * b.w;
  }
  // pre-split this row of x: lane e handles elems [e*16, e*16+16) (L1-hot)
  {
    bf16x8 h0, l0, h1, l1;
    cvt_split8(xr[e * 4 + 0], xr[e * 4 + 1], h0, l0);
    cvt_split8(xr[e * 4 + 2], xr[e * 4 + 3], h1, l1);
    __bf16* xh = x_hi + (size_t)t * D_DIM + e * 16;
    __bf16* xl = x_lo + (size_t)t * D_DIM + e * 16;
    *(bf16x8*)(xh) = h0; *(bf16x8*)(xh + 8) = h1;
    *(bf16x8*)(xl) = l0; *(bf16x8*)(xl + 8) = l1;
  }
  float m = acc;
  for (int off = 32; off; off >>= 1) m = fmaxf(m, __shfl_xor(m, off, 64));
  float p = __expf(acc - m);
  float s = p;
  for (int off = 32; off; off >>= 1) s += __shfl_xor(s, off, 64);
  float prob = p / s;

  float val = prob;
  int ids[TOPK];
  float ws[TOPK];
  float wsum = 0.f;
#pragma unroll
  for (int k = 0; k < TOPK; k++) {
    float v = val;
    int idx = e;
    for (int off = 32; off; off >>= 1) {
      float ov = __shfl_xor(v, off, 64);
      int oi = __shfl_xor(idx, off, 64);
      if (ov > v || (ov == v && oi < idx)) { v = ov; idx = oi; }
    }
    ids[k] = idx;
    ws[k] = v;
    wsum += v;
    if (e == idx) val = -1.f;
  }
  if (e < TOPK) {
    const int k = e;
    const int ex = ids[k];
    const float w = ws[k] / wsum;
    const int p_id = t * TOPK + k;
    pairw[p_id] = w;
    const int pos = atomicAdd(&cnt[ex], 1);
    list[ex * T_TOK + pos] = p_id;
  }
}

// ---------------- Stage 1: gate+up GEMM + SiLU (split-bf16 MFMA) ----------
// grid (E=64, INTER/32=16), 256 threads (4 waves). Tile 32f x 64t, BK=64.
// LDS: WEIGHTS ONLY, 2 x 16KB (double-buffered). Units of 16B:
//   wg_hi [0,256) wg_lo [256,512) wu_hi [512,768) wu_lo [768,1024)
// XOR swizzle: (row, blk8) at unit row*8 + (blk ^ (row&7))  [0 conflicts, r3].
// Weights: 2-deep reg prefetch (wA/wB) -> convert once -> ds_write; the
// convert of W(k+1) runs at iter k on data loaded at iter k-1 (latency hidden).
// x: per-lane global->reg B-fragments (L2-hot), prefetched 1 K-tile ahead.
// NOTE: no forced min-occupancy (r4/r5 container deaths suspected from
// __launch_bounds__(256,4) spill-thrash); compiler-chosen VGPR count.
#define BF1 32
#define BT1 64
#define NK1 (D_DIM / 64)
__global__ __launch_bounds__(256) void stage1_kernel(
    const __bf16* __restrict__ x_hi, const __bf16* __restrict__ x_lo,
    const float* __restrict__ w_gate, const float* __restrict__ w_up,
    const int* __restrict__ cnt, const int* __restrict__ list,
    const float* __restrict__ pairw,
    __bf16* __restrict__ h_hi, __bf16* __restrict__ h_lo) {
  const int e = blockIdx.x;
  const int fbase = blockIdx.y * BF1;
  const int n = cnt[e];
  if (n == 0) return;
  __shared__ bf16x8 lds[2][1024];  // 32 KB total
  const int tid = threadIdx.x;
  const int w = tid >> 6;
  const int lane = tid & 63;
  const int lrow = lane & 15;
  const int lk = lane >> 4;
  const int* mylist = list + e * T_TOK;

  // weight staging: thread owns (row wrow, blk wblk) of both wg and wu
  const int wrow = tid >> 3;  // 0..31
  const int wblk = tid & 7;
  const float* gsrc = w_gate + ((size_t)e * INTER + fbase + wrow) * D_DIM + wblk * 8;
  const float* usrc = w_up + ((size_t)e * INTER + fbase + wrow) * D_DIM + wblk * 8;
  const int wunit = wrow * 8 + (wblk ^ (wrow & 7));

  float4 wA[4], wB[4];
  bf16x8 xA[4], xB[4];

  for (int tb = 0; tb < n; tb += BT1) {
    const bool active = (tb + w * 16) < n;  // wave-uniform
    const int slot1 = tb + w * 16 + lrow;
    const int pidx = mylist[(slot1 < n) ? slot1 : 0];
    const __bf16* xbh = x_hi + (size_t)(pidx >> 2) * D_DIM + lk * 8;
    const __bf16* xbl = x_lo + (size_t)(pidx >> 2) * D_DIM + lk * 8;

    auto LOADW = [&](float4* r, int kt) {
      const float4* g4 = (const float4*)(gsrc + kt * 64);
      const float4* u4 = (const float4*)(usrc + kt * 64);
      r[0] = g4[0]; r[1] = g4[1]; r[2] = u4[0]; r[3] = u4[1];
    };
    auto LOADX = [&](bf16x8* r, int kt) {
      r[0] = *(const bf16x8*)(xbh + kt * 64);
      r[1] = *(const bf16x8*)(xbl + kt * 64);
      r[2] = *(const bf16x8*)(xbh + kt * 64 + 32);
      r[3] = *(const bf16x8*)(xbl + kt * 64 + 32);
    };
    auto CVTW = [&](const float4* r, int buf) {
      bf16x8 h0, l0;
      cvt_split8(r[0], r[1], h0, l0);
      lds[buf][wunit] = h0;
      lds[buf][wunit + 256] = l0;
      cvt_split8(r[2], r[3], h0, l0);
      lds[buf][wunit + 512] = h0;
      lds[buf][wunit + 768] = l0;
    };

    f32x4 accg[2] = {};
    f32x4 accu[2] = {};

    auto COMPUTE = [&](int buf, const bf16x8* xr) {
      if (!active) return;
      const bf16x8* U = &lds[buf][0];
#pragma unroll
      for (int s = 0; s < 2; s++) {
        const bf16x8 xh = xr[s * 2];
        const bf16x8 xl = xr[s * 2 + 1];
        const int blk = s * 4 + lk;
#pragma unroll
        for (int i = 0; i < 2; i++) {
          const int fr = i * 16 + lrow;
          const int fu = fr * 8 + (blk ^ (fr & 7));
          const bf16x8 gh = U[fu];
          const bf16x8 gl = U[fu + 256];
          const bf16x8 uh = U[fu + 512];
          const bf16x8 ul = U[fu + 768];
          accg[i] = __builtin_amdgcn_mfma_f32_16x16x32_bf16(gh, xh, accg[i], 0, 0, 0);
          accg[i] = __builtin_amdgcn_mfma_f32_16x16x32_bf16(gh, xl, accg[i], 0, 0, 0);
          accg[i] = __builtin_amdgcn_mfma_f32_16x16x32_bf16(gl, xh, accg[i], 0, 0, 0);
          accu[i] = __builtin_amdgcn_mfma_f32_16x16x32_bf16(uh, xh, accu[i], 0, 0, 0);
          accu[i] = __builtin_amdgcn_mfma_f32_16x16x32_bf16(uh, xl, accu[i], 0, 0, 0);
          accu[i] = __builtin_amdgcn_mfma_f32_16x16x32_bf16(ul, xh, accu[i], 0, 0, 0);
        }
      }
    };

    // prologue: W(0),W(1) in flight; convert W(0); x(0),x(1) in flight
    LOADW(wA, 0);
    LOADW(wB, 1);
    if (active) LOADX(xA, 0);
    CVTW(wA, 0);
    if (active) LOADX(xB, 1);

    for (int ki = 0; ki < NK1; ki += 2) {
      __syncthreads();                    // buf0 = W(ki) ready
      if (ki + 2 < NK1) LOADW(wA, ki + 2);
      COMPUTE(0, xA);
      CVTW(wB, 1);                        // W(ki+1) -> buf1 (loaded 1 iter ago)
      if (active && ki + 2 < NK1) LOADX(xA, ki + 2);
      __syncthreads();                    // buf1 = W(ki+1) ready
      if (ki + 3 < NK1) LOADW(wB, ki + 3);
      COMPUTE(1, xB);
      if (ki + 2 < NK1) CVTW(wA, 0);      // W(ki+2) -> buf0
      if (active && ki + 3 < NK1) LOADX(xB, ki + 3);
    }
    // epilogue: h[p][f] = w_p * silu(g) * u, bf16 hi + SCALED lo (x256)
    // D frag: token = lane&15 (wave's group), f = i*16 + lk*4 + r
    if (slot1 < n) {
      const float wp = pairw[pidx];
      __bf16* hh = h_hi + (size_t)pidx * INTER + fbase;
      __bf16* hl = h_lo + (size_t)pidx * INTER + fbase;
#pragma unroll
      for (int i = 0; i < 2; i++) {
        bf16x4 vh, vl;
#pragma unroll
        for (int r = 0; r < 4; r++) {
          const float g = accg[i][r];
          const float u = accu[i][r];
          const float v = wp * (g / (1.f + __expf(-g))) * u;
          const __bf16 hv = (__bf16)v;
          vh[r] = hv;
          vl[r] = (__bf16)((v - (float)hv) * 256.f);
        }
        *(bf16x4*)(hh + i * 16 + lk * 4) = vh;
        *(bf16x4*)(hl + i * 16 + lk * 4) = vl;
      }
    }
  }
}

// ---------------- Stage 2: down GEMM (split-bf16 MFMA), atomic accum ------
// grid (E=64, D/64=16), 256 threads. Tile 64d x 64t, BK=64.
// LDS: wd only, 2 x 16KB: wd_hi [0,512) wd_lo [512,1024) units.
// h: per-lane global->reg (bf16 hi + scaled lo), prefetched 1 K-tile ahead.
// Products: acc += wh*hh + wl*hh ; accb += wh*hl_scaled ; out = acc+accb/256.
#define BF2 64
#define BT2 64
#define NK2 (INTER / 64)
__global__ __launch_bounds__(256) void stage2_kernel(
    const float* __restrict__ w_down, const int* __restrict__ cnt,
    const int* __restrict__ list, const __bf16* __restrict__ h_hi,
    const __bf16* __restrict__ h_lo, float* __restrict__ out) {
  const int e = blockIdx.x;
  const int dbase = blockIdx.y * BF2;
  const int n = cnt[e];
  if (n == 0) return;
  __shared__ bf16x8 lds[2][1024];  // 32 KB total
  const int tid = threadIdx.x;
  const int w = tid >> 6;
  const int lane = tid & 63;
  const int lrow = lane & 15;
  const int lk = lane >> 4;
  const int* mylist = list + e * T_TOK;

  // wd staging: thread owns rows wrow and wrow+32 at blk wblk
  const int wrow = tid >> 3;  // 0..31
  const int wblk = tid & 7;
  const float* dsrc0 = w_down + ((size_t)e * D_DIM + dbase + wrow) * INTER + wblk * 8;
  const float* dsrc1 = dsrc0 + (size_t)32 * INTER;
  const int wunit0 = wrow * 8 + (wblk ^ (wrow & 7));
  const int wunit1 = wunit0 + 256;  // (wrow+32)&7 == wrow&7

  float4 wA[4], wB[4];
  bf16x8 hA[4], hB[4];

  for (int tb = 0; tb < n; tb += BT2) {
    const bool active = (tb + w * 16) < n;
    const int slot1 = tb + w * 16 + lrow;
    const int pidx = mylist[(slot1 < n) ? slot1 : 0];
    const __bf16* hbh = h_hi + (size_t)pidx * INTER + lk * 8;
    const __bf16* hbl = h_lo + (size_t)pidx * INTER + lk * 8;

    auto LOADW = [&](float4* r, int kt) {
      const float4* a4 = (const float4*)(dsrc0 + kt * 64);
      const float4* b4 = (const float4*)(dsrc1 + kt * 64);
      r[0] = a4[0]; r[1] = a4[1]; r[2] = b4[0]; r[3] = b4[1];
    };
    auto LOADH = [&](bf16x8* r, int kt) {
      r[0] = *(const bf16x8*)(hbh + kt * 64);
      r[1] = *(const bf16x8*)(hbl + kt * 64);
      r[2] = *(const bf16x8*)(hbh + kt * 64 + 32);
      r[3] = *(const bf16x8*)(hbl + kt * 64 + 32);
    };
    auto CVTW = [&](const float4* r, int buf) {
      bf16x8 h0, l0;
      cvt_split8(r[0], r[1], h0, l0);
      lds[buf][wunit0] = h0;
      lds[buf][wunit0 + 512] = l0;
      cvt_split8(r[2], r[3], h0, l0);
      lds[buf][wunit1] = h0;
      lds[buf][wunit1 + 512] = l0;
    };

    f32x4 acc[4] = {};
    f32x4 accb[4] = {};

    auto COMPUTE = [&](int buf, const bf16x8* hr) {
      if (!active) return;
      const bf16x8* U = &lds[buf][0];
#pragma unroll
      for (int s = 0; s < 2; s++) {
        const bf16x8 hh = hr[s * 2];
        const bf16x8 hl = hr[s * 2 + 1];
        const int blk = s * 4 + lk;
#pragma unroll
        for (int i = 0; i < 4; i++) {
          const int dr = i * 16 + lrow;
          const int du = dr * 8 + (blk ^ (dr & 7));
          const bf16x8 wh = U[du];
          const bf16x8 wl = U[du + 512];
          acc[i] = __builtin_amdgcn_mfma_f32_16x16x32_bf16(wh, hh, acc[i], 0, 0, 0);
          acc[i] = __builtin_amdgcn_mfma_f32_16x16x32_bf16(wl, hh, acc[i], 0, 0, 0);
          accb[i] = __builtin_amdgcn_mfma_f32_16x16x32_bf16(wh, hl, accb[i], 0, 0, 0);
        }
      }
    };

    LOADW(wA, 0);
    LOADW(wB, 1);
    if (active) LOADH(hA, 0);
    CVTW(wA, 0);
    if (active) LOADH(hB, 1);

    for (int ki = 0; ki < NK2; ki += 2) {
      __syncthreads();
      if (ki + 2 < NK2) LOADW(wA, ki + 2);
      COMPUTE(0, hA);
      CVTW(wB, 1);
      if (active && ki + 2 < NK2) LOADH(hA, ki + 2);
      __syncthreads();
      if (ki + 3 < NK2) LOADW(wB, ki + 3);
      COMPUTE(1, hB);
      if (ki + 2 < NK2) CVTW(wA, 0);
      if (active && ki + 3 < NK2) LOADH(hB, ki + 3);
    }
    // epilogue: atomic accumulate (combine weight folded into h)
    // D frag: token = lane&15, d = i*16 + lk*4 + r
    if (slot1 < n) {
      const int tok = pidx >> 2;
      float* op = out + (size_t)tok * D_DIM + dbase;
#pragma unroll
      for (int i = 0; i < 4; i++) {
#pragma unroll
        for (int r = 0; r < 4; r++)
          atomicAdd(&op[i * 16 + lk * 4 + r], acc[i][r] + accb[i][r] * 0.00390625f);
      }
    }
  }
}

extern "C" void kernel_launch(void* const* d_in, const int* in_sizes, int n_in,
                              void* d_out, int out_size, void* d_ws, size_t ws_size,
                              hipStream_t stream) {
  const float* x = (const float*)d_in[0];
  const float* gate_w = (const float*)d_in[1];
  const float* w_gate = (const float*)d_in[2];
  const float* w_up = (const float*)d_in[3];
  const float* w_down = (const float*)d_in[4];
  float* out = (float*)d_out;

  char* ws = (char*)d_ws;
  size_t off = 0;
  int* cnt = (int*)(ws + off); off += 256;
  int* list = (int*)(ws + off); off += (size_t)E_EXP * T_TOK * 4;
  float* pairw = (float*)(ws + off); off += (size_t)T_TOK * TOPK * 4;
  __bf16* h_hi = (__bf16*)(ws + off); off += (size_t)T_TOK * TOPK * INTER * 2;
  __bf16* h_lo = (__bf16*)(ws + off); off += (size_t)T_TOK * TOPK * INTER * 2;
  __bf16* x_hi = (__bf16*)(ws + off); off += (size_t)T_TOK * D_DIM * 2;
  __bf16* x_lo = (__bf16*)(ws + off); off += (size_t)T_TOK * D_DIM * 2;

  hipMemsetAsync(cnt, 0, E_EXP * sizeof(int), stream);
  hipMemsetAsync(out, 0, (size_t)T_TOK * D_DIM * sizeof(float), stream);

  router_kernel<<<T_TOK, 64, 0, stream>>>(x, gate_w, cnt, list, pairw, x_hi, x_lo);
  stage1_kernel<<<dim3(E_EXP, INTER / BF1), 256, 0, stream>>>(
      x_hi, x_lo, w_gate, w_up, cnt, list, pairw, h_hi, h_lo);
  stage2_kernel<<<dim3(E_EXP, D_DIM / BF2), 256, 0, stream>>>(
      w_down, cnt, list, h_hi, h_lo, out);
}